// Round 1
// baseline (170.919 us; speedup 1.0000x reference)
//
#include <hip/hip_runtime.h>
#include <math.h>

#define N_PTS   8192
#define KNN     30
#define CAPG    104     // max stored candidates per group (lambda=48, +8 sigma)
#define STR     105     // LDS row stride in u64
#define GROUPS  8       // queries per block
#define BLOCK   128     // 2 waves per block
#define NZ      64
#define NY      64
#define NBKT    (NZ * NY)
#define CLO     -4.0f
#define CSC     8.0f    // buckets per unit: bucket = floor((c - CLO) * CSC)
#define LAMBDA  48.0f

// ws layout (bytes):
//   S      f4[4*8192]      @ 0        (512 KB)
//   O      i32[4*8192]     @ 524288   (128 KB)
//   bstart i32[4*4097]     @ 655360   (65552 B)
//   ghist  i32[4*4096]     @ 720912   (65536 B)  -- zeroed via hipMemsetAsync
//   gcur   i32[4*4096]     @ 786448   (65536 B)
#define WS_S   0
#define WS_O   524288
#define WS_BS  655360
#define WS_GH  720912
#define WS_GC  786448

__device__ __forceinline__ int clampi(int v, int lo, int hi) {
    return v < lo ? lo : (v > hi ? hi : v);
}
__device__ __forceinline__ int bucket_of(float pz, float py) {
    int zb = clampi((int)floorf((pz - CLO) * CSC), 0, NZ - 1);
    int yb = clampi((int)floorf((py - CLO) * CSC), 0, NY - 1);
    return (zb << 6) | yb;
}

// ---------------------------------------------------------------------------
// Prep phase A: full-chip. Copy x -> out ch0..2, histogram buckets via global
// atomics (ghist must be pre-zeroed). grid 128 x 256.
// ---------------------------------------------------------------------------
__global__ __launch_bounds__(256) void prep_hist_kernel(const float* __restrict__ x,
                                                        float* __restrict__ out,
                                                        int* __restrict__ ghist) {
    const int i = blockIdx.x * 256 + threadIdx.x;     // 0..32767
    const int b = i >> 13;
    const int p = i & (N_PTS - 1);
    const float* xb = x + (size_t)b * 3 * N_PTS;
    float* ob = out + (size_t)b * 6 * N_PTS;
    float px = xb[p], py = xb[N_PTS + p], pz = xb[2 * N_PTS + p];
    ob[p]             = px;
    ob[N_PTS + p]     = py;
    ob[2 * N_PTS + p] = pz;
    atomicAdd(&ghist[(b << 12) + bucket_of(pz, py)], 1);
}

// ---------------------------------------------------------------------------
// Prep phase B: per-batch exclusive scan of 4096-bucket histogram.
// 4 blocks x 1024 threads; thread t owns buckets 4t..4t+3.
// Writes bstart (for knn) and gcur (scatter cursors).
// ---------------------------------------------------------------------------
__global__ __launch_bounds__(1024) void prep_scan_kernel(const int* __restrict__ ghist,
                                                         int* __restrict__ bstart,
                                                         int* __restrict__ gcur) {
    __shared__ int wsum[16];
    const int b = blockIdx.x;
    const int t = threadIdx.x;
    const int wid = t >> 6, lane = t & 63;
    const int* gh = ghist + (b << 12);

    int l0 = gh[4 * t], l1 = gh[4 * t + 1], l2 = gh[4 * t + 2], l3 = gh[4 * t + 3];
    int s = l0 + l1 + l2 + l3;
    int sum = s;
    #pragma unroll
    for (int off = 1; off < 64; off <<= 1) {
        int v = __shfl_up(sum, off);
        if (lane >= off) sum += v;
    }
    if (lane == 63) wsum[wid] = sum;
    __syncthreads();
    if (t == 0) {
        int run = 0;
        #pragma unroll
        for (int k = 0; k < 16; ++k) { int v = wsum[k]; wsum[k] = run; run += v; }
    }
    __syncthreads();
    int base = wsum[wid] + (sum - s);     // exclusive prefix for this thread
    int b0 = base, b1 = base + l0, b2 = b1 + l1, b3 = b2 + l2;
    int* bsb = bstart + b * (NBKT + 1);
    int* gc  = gcur + (b << 12);
    bsb[4 * t] = b0; bsb[4 * t + 1] = b1; bsb[4 * t + 2] = b2; bsb[4 * t + 3] = b3;
    gc[4 * t]  = b0; gc[4 * t + 1]  = b1; gc[4 * t + 2]  = b2; gc[4 * t + 3]  = b3;
    if (t == 1023) bsb[NBKT] = N_PTS;
}

// ---------------------------------------------------------------------------
// Prep phase C: full-chip scatter via global bucket cursors. grid 128 x 256.
// Order within a bucket is nondeterministic, but keys carry orig idx so the
// top-30 selection is order-independent.
// ---------------------------------------------------------------------------
__global__ __launch_bounds__(256) void prep_scatter_kernel(const float* __restrict__ x,
                                                           float4* __restrict__ S,
                                                           int* __restrict__ O,
                                                           int* __restrict__ gcur) {
    const int i = blockIdx.x * 256 + threadIdx.x;     // 0..32767
    const int b = i >> 13;
    const int p = i & (N_PTS - 1);
    const float* xb = x + (size_t)b * 3 * N_PTS;
    float px = xb[p], py = xb[N_PTS + p], pz = xb[2 * N_PTS + p];
    int bk = bucket_of(pz, py);
    int dst = atomicAdd(&gcur[(b << 12) + bk], 1);
    float xx = __fadd_rn(__fadd_rn(__fmul_rn(px, px), __fmul_rn(py, py)),
                         __fmul_rn(pz, pz));
    S[((size_t)b << 13) + dst] = make_float4(px, py, pz, xx);
    O[((size_t)b << 13) + dst] = p;
}

// ---------------------------------------------------------------------------
// Main: 16 lanes/query, 8 queries/block. Lane-parallel radius solve; 2x-unrolled
// (z,y)-window segment scan; ballot-compact u64 keys; register-cached rank
// select; fp64 epilogue. No block barrier: all LDS traffic is intra-wave.
// ---------------------------------------------------------------------------
__global__ __launch_bounds__(BLOCK, 6) void knn_normal_kernel(const float4* __restrict__ S,
                                                              const int* __restrict__ O,
                                                              const int* __restrict__ bstart,
                                                              float* __restrict__ out) {
    __shared__ unsigned long long ldk[GROUPS * STR];

    const int t    = threadIdx.x;
    const int l16  = t & 15;
    const int g    = t >> 4;
    const int gsh  = (t & 63) & ~15;
    const int qblk = (blockIdx.x * 1031) & 4095;   // bijective swizzle: flatten tail
    const int qid  = qblk * GROUPS + g;
    const int b    = qid >> 13;
    const int pos  = qid & (N_PTS - 1);
    const float4* __restrict__ P  = S + ((size_t)b << 13);
    const int*    __restrict__ Ob = O + ((size_t)b << 13);
    const int*    __restrict__ bs = bstart + b * (NBKT + 1);
    const float4 qp = P[pos];
    const int    oi = Ob[pos];

    unsigned long long* __restrict__ ldg = ldk + g * STR;

    // ---- radius: solve lambda(r)=48 (Gaussian ball mass), lane-parallel Simpson-9
    const float c = fmaxf(sqrtf(qp.w), 1e-3f);
    float rlo = 0.05f, rhi = 6.0f;
    for (int it = 0; it < 12; ++it) {
        float r = 0.5f * (rlo + rhi);
        float slo = fmaxf(c - r, 0.0f);
        float h = (c + r - slo) * 0.125f;
        float f = 0.0f;
        if (l16 <= 8) {
            float sq = slo + h * (float)l16;
            float cs = c - sq;
            float hh = fmaxf(fminf((r * r - cs * cs) * (0.5f / c), 2.0f * sq), 0.0f);
            float w = (l16 == 0 || l16 == 8) ? 1.0f : ((l16 & 1) ? 4.0f : 2.0f);
            f = w * __expf(-0.5f * sq * sq) * sq * hh;
        }
        f += __shfl_xor(f, 1, 16); f += __shfl_xor(f, 2, 16);
        f += __shfl_xor(f, 4, 16); f += __shfl_xor(f, 8, 16);
        float lam = 1089.3f * f * h;       // 520.1 * 2*pi / 3
        if (lam < LAMBDA) rlo = r; else rhi = r;
    }
    float rad = rhi * 1.02f;
    float r2  = rad * rad;

    int  cnt = 0;
    bool active = true;

    for (;;) {
        if (active) {
            cnt = 0;
            float w = __fmaf_rn(sqrtf(r2), 1.002f, 1e-3f);   // guard band
            int zlo = clampi((int)floorf((qp.z - w - CLO) * CSC), 0, NZ - 1);
            int zhi = clampi((int)floorf((qp.z + w - CLO) * CSC), 0, NZ - 1);
            int ylo = clampi((int)floorf((qp.y - w - CLO) * CSC), 0, NY - 1);
            int yhi = clampi((int)floorf((qp.y + w - CLO) * CSC), 0, NY - 1);
            for (int zb = zlo; zb <= zhi; ++zb) {
                int lo = bs[(zb << 6) + ylo];
                int hi = bs[(zb << 6) + yhi + 1];
                int smax = (hi - lo + 31) >> 5;   // group-uniform, 32 cand/iter
                for (int s = 0; s < smax; ++s) {
                    int j1  = lo + (s << 5) + l16;
                    int j2  = j1 + 16;
                    int jc1 = j1 < hi ? j1 : hi - 1;
                    int jc2 = j2 < hi ? j2 : hi - 1;
                    float4 p1 = P[jc1];
                    float4 p2 = P[jc2];
                    float mm1 = __fmaf_rn(qp.z, p1.z, __fmaf_rn(qp.y, p1.y, __fmul_rn(qp.x, p1.x)));
                    float d1  = __fsub_rn(__fadd_rn(qp.w, p1.w), __fmul_rn(2.0f, mm1));
                    float mm2 = __fmaf_rn(qp.z, p2.z, __fmaf_rn(qp.y, p2.y, __fmul_rn(qp.x, p2.x)));
                    float d2  = __fsub_rn(__fadd_rn(qp.w, p2.w), __fmul_rn(2.0f, mm2));
                    bool hit1 = (j1 < hi) && (d1 <= r2);
                    bool hit2 = (j2 < hi) && (d2 <= r2);
                    unsigned long long m1 = __ballot(hit1);
                    unsigned sub1 = (unsigned)((m1 >> gsh) & 0xFFFFull);
                    if (hit1) {
                        int slot = cnt + __popc(sub1 & ((1u << l16) - 1u));
                        if (slot < CAPG) {
                            unsigned u = __float_as_uint(d1);
                            u = (u & 0x80000000u) ? ~u : (u | 0x80000000u);
                            ldg[slot] = ((unsigned long long)u << 28) | (unsigned long long)jc1;
                        }
                    }
                    cnt += __popc(sub1);
                    unsigned long long m2 = __ballot(hit2);
                    unsigned sub2 = (unsigned)((m2 >> gsh) & 0xFFFFull);
                    if (hit2) {
                        int slot = cnt + __popc(sub2 & ((1u << l16) - 1u));
                        if (slot < CAPG) {
                            unsigned u = __float_as_uint(d2);
                            u = (u & 0x80000000u) ? ~u : (u | 0x80000000u);
                            ldg[slot] = ((unsigned long long)u << 28) | (unsigned long long)jc2;
                        }
                    }
                    cnt += __popc(sub2);
                }
            }
        }
        bool bad = active && (cnt < KNN || cnt > CAPG);
        if (__ballot(bad) == 0ULL) break;         // wave-uniform exit
        active = bad;
        if (active) r2 = (cnt < KNN) ? r2 * 1.6f : r2 * 0.82f;
    }

    // ---- fill orig-idx field (bits 14..27) so u64 order == lex (d, orig idx).
    // Own keys stay cached in registers; absent slots get ~0 (rank >= cnt -> excluded).
    unsigned long long k0 = ~0ULL, k1 = ~0ULL, k2 = ~0ULL, k3 = ~0ULL,
                       k4 = ~0ULL, k5 = ~0ULL, k6 = ~0ULL;
    #define FILLK(J, KV) { int idx = l16 + 16 * (J); if (idx < cnt) {            \
        unsigned long long key = ldg[idx];                                       \
        int jc = (int)(key & 0x3FFFull);                                         \
        KV = (key & ~0x0FFFFFFFull) | ((unsigned long long)Ob[jc] << 14)         \
             | (unsigned long long)jc;                                           \
        ldg[idx] = KV; } }
    FILLK(0, k0) FILLK(1, k1) FILLK(2, k2) FILLK(3, k3)
    FILLK(4, k4) FILLK(5, k5) FILLK(6, k6)
    #undef FILLK
    __builtin_amdgcn_wave_barrier();   // intra-wave LDS traffic only; no block barrier

    // ---- stable top-30: rank register keys against all keys (u-outer, broadcast read)
    int r0 = 0, r1 = 0, r2i = 0, r3 = 0, r4 = 0, r5 = 0, r6 = 0;
    if (cnt <= 64) {
        for (int u = 0; u < cnt; ++u) {
            unsigned long long ku = ldg[u];
            r0 += ku < k0; r1 += ku < k1; r2i += ku < k2; r3 += ku < k3;
        }
        r4 = r5 = r6 = KNN;
    } else {
        for (int u = 0; u < cnt; ++u) {
            unsigned long long ku = ldg[u];
            r0 += ku < k0; r1 += ku < k1; r2i += ku < k2; r3 += ku < k3;
            r4 += ku < k4; r5 += ku < k5; r6 += ku < k6;
        }
    }

    const double qx = (double)qp.x, qy = (double)qp.y, qz = (double)qp.z;
    double sx = 0.0, sy = 0.0, sz = 0.0;
    double sxx = 0.0, sxy = 0.0, sxz = 0.0, syy = 0.0, syz = 0.0, szz = 0.0;

    #define ACCJ(KV, RV) if ((RV) < KNN) {                                       \
        float4 p = P[(int)((KV) & 0x3FFFull)];                                   \
        double ax = (double)p.x - qx, ay = (double)p.y - qy, az = (double)p.z - qz; \
        sx += ax; sy += ay; sz += az;                                            \
        sxx = fma(ax, ax, sxx); sxy = fma(ax, ay, sxy); sxz = fma(ax, az, sxz);  \
        syy = fma(ay, ay, syy); syz = fma(ay, az, syz); szz = fma(az, az, szz); }
    ACCJ(k0, r0) ACCJ(k1, r1) ACCJ(k2, r2i) ACCJ(k3, r3)
    ACCJ(k4, r4) ACCJ(k5, r5) ACCJ(k6, r6)
    #undef ACCJ

    #pragma unroll
    for (int off = 1; off < 16; off <<= 1) {
        sx  += __shfl_xor(sx,  off, 16); sy  += __shfl_xor(sy,  off, 16); sz  += __shfl_xor(sz,  off, 16);
        sxx += __shfl_xor(sxx, off, 16); sxy += __shfl_xor(sxy, off, 16); sxz += __shfl_xor(sxz, off, 16);
        syy += __shfl_xor(syy, off, 16); syz += __shfl_xor(syz, off, 16); szz += __shfl_xor(szz, off, 16);
    }

    if (l16 == 0) {
        const double kinv = 1.0 / (double)KNN;
        double m00 = sxx - sx * sx * kinv;
        double m11 = syy - sy * sy * kinv;
        double m22 = szz - sz * sz * kinv;
        double m01 = sxy - sx * sy * kinv;
        double m02 = sxz - sx * sz * kinv;
        double m12 = syz - sy * sz * kinv;

        double nx = 1.0, ny = 0.0, nz = 0.0;
        double q3 = (m00 + m11 + m22) / 3.0;
        double p1 = m01 * m01 + m02 * m02 + m12 * m12;
        double d00 = m00 - q3, d11 = m11 - q3, d22 = m22 - q3;
        double p2 = d00 * d00 + d11 * d11 + d22 * d22 + 2.0 * p1;
        if (p2 > 1e-280) {
            double pp = sqrt(p2 / 6.0);
            double ip = 1.0 / pp;
            double b00 = d00 * ip, b11 = d11 * ip, b22 = d22 * ip;
            double b01 = m01 * ip, b02 = m02 * ip, b12 = m12 * ip;
            double detB = b00 * (b11 * b22 - b12 * b12)
                        - b01 * (b01 * b22 - b12 * b02)
                        + b02 * (b01 * b12 - b11 * b02);
            double rr = 0.5 * detB;
            rr = rr < -1.0 ? -1.0 : (rr > 1.0 ? 1.0 : rr);
            double phi = acos(rr) / 3.0;
            double lam = q3 + 2.0 * pp * cos(phi + 2.0943951023931953); // smallest eig
            double a00 = m00 - lam, a11 = m11 - lam, a22 = m22 - lam;
            double v0x = m01 * m12 - m02 * a11, v0y = m02 * m01 - a00 * m12, v0z = a00 * a11 - m01 * m01;
            double v1x = m01 * a22 - m02 * m12, v1y = m02 * m02 - a00 * a22, v1z = a00 * m12 - m01 * m02;
            double v2x = a11 * a22 - m12 * m12, v2y = m12 * m02 - m01 * a22, v2z = m01 * m12 - a11 * m02;
            double n0 = v0x * v0x + v0y * v0y + v0z * v0z;
            double n1 = v1x * v1x + v1y * v1y + v1z * v1z;
            double n2 = v2x * v2x + v2y * v2y + v2z * v2z;
            double bx = v0x, by = v0y, bz = v0z, bn = n0;
            if (n1 > bn) { bx = v1x; by = v1y; bz = v1z; bn = n1; }
            if (n2 > bn) { bx = v2x; by = v2y; bz = v2z; bn = n2; }
            if (bn > 1e-280) {
                double inv = 1.0 / sqrt(bn);
                nx = bx * inv; ny = by * inv; nz = bz * inv;
            }
        }
        double dq = -(qx * nx + qy * ny + qz * nz);
        if (dq < 0.0) { nx = -nx; ny = -ny; nz = -nz; }

        float* ob = out + (size_t)b * 6 * N_PTS;
        ob[3 * N_PTS + oi] = (float)nx;
        ob[4 * N_PTS + oi] = (float)ny;
        ob[5 * N_PTS + oi] = (float)nz;
    }
}

// ---------------------------------------------------------------------------
extern "C" void kernel_launch(void* const* d_in, const int* in_sizes, int n_in,
                              void* d_out, int out_size, void* d_ws, size_t ws_size,
                              hipStream_t stream) {
    const float* x = (const float*)d_in[0];
    float* out = (float*)d_out;
    char* ws = (char*)d_ws;
    float4* S    = (float4*)(ws + WS_S);
    int*    O    = (int*)(ws + WS_O);
    int*    bsta = (int*)(ws + WS_BS);
    int*    gh   = (int*)(ws + WS_GH);
    int*    gc   = (int*)(ws + WS_GC);

    hipMemsetAsync(gh, 0, 4 * NBKT * sizeof(int), stream);
    prep_hist_kernel   <<<dim3(128), dim3(256),  0, stream>>>(x, out, gh);
    prep_scan_kernel   <<<dim3(4),   dim3(1024), 0, stream>>>(gh, bsta, gc);
    prep_scatter_kernel<<<dim3(128), dim3(256),  0, stream>>>(x, S, O, gc);
    knn_normal_kernel  <<<dim3(32768 / GROUPS), dim3(BLOCK), 0, stream>>>(S, O, bsta, out);
}